// Round 1
// baseline (2750.758 us; speedup 1.0000x reference)
//
#include <hip/hip_runtime.h>
#include <math.h>
#include <stdint.h>

#define NTOK 32768
#define KCB  4096
#define DIM  256

// ---------------------------------------------------------------------------
// K0: numpy-exact squared-norm rows for x (NTOK rows) and codebook (KCB rows).
// numpy pairwise sum for n=256: two halves of 128; each half uses 8 serial
// accumulators r[j] = sum_i a[128h + 8i + j], combined as
// ((r0+r1)+(r2+r3)) + ((r4+r5)+(r6+r7)); total = left + right.
// 16 threads per row (h in {0,1} x j in {0..7}).
// ---------------------------------------------------------------------------
__global__ __launch_bounds__(256) void norms_kernel(
    const float* __restrict__ x, const float* __restrict__ cb,
    float* __restrict__ xnorm, float* __restrict__ cnorm) {
#pragma clang fp contract(off)
    int gid = blockIdx.x * 256 + threadIdx.x;
    int row = gid >> 4;              // 0 .. NTOK+KCB-1 (grid sized exactly)
    int h   = (gid >> 3) & 1;
    int j   = gid & 7;

    const float* src;
    float* dst;
    if (row < NTOK) { src = x  + (size_t)row * DIM;          dst = xnorm + row; }
    else            { int r = row - NTOK;
                      src = cb + (size_t)r   * DIM;          dst = cnorm + r;   }

    const float* p = src + h * 128 + j;
    float r0 = 0.0f;
    for (int i = 0; i < 16; ++i) {
        float v = p[8 * i];
        float pr = v * v;            // rounded product (np does xf*xf first)
        r0 = r0 + pr;                // serial ascending, no fma (contract off)
    }
    __shared__ float sh[256];
    sh[threadIdx.x] = r0;
    __syncthreads();
    if ((threadIdx.x & 15) == 0) {
        const float* q = &sh[threadIdx.x];   // q[h*8+j]
        float left  = ((q[0] + q[1]) + (q[2] + q[3])) + ((q[4] + q[5]) + (q[6] + q[7]));
        float right = ((q[8] + q[9]) + (q[10] + q[11])) + ((q[12] + q[13]) + (q[14] + q[15]));
        *dst = left + right;
    }
}

// ---------------------------------------------------------------------------
// K1: dist[n][k] = sqrt(max((xn[n]+cn[k]) - 2*(x[n].c[k]), 0))  (fp32 GEMM-NT)
// 128x128 block tile, 256 threads, 8x8 micro-tile (split 4+4 to keep LDS
// reads 2-way-conflict-free and global stores float4-coalesced).
// ---------------------------------------------------------------------------
__global__ __launch_bounds__(256) void gemm1_kernel(
    const float* __restrict__ x, const float* __restrict__ cb,
    const float* __restrict__ xnorm, const float* __restrict__ cnorm,
    float* __restrict__ dist_out) {
#pragma clang fp contract(off)
    __shared__ float Xs[16][132];
    __shared__ float Cs[16][132];

    const int t  = threadIdx.x;
    const int tx = t & 15, ty = t >> 4;
    const int n0 = blockIdx.y * 128;
    const int k0 = blockIdx.x * 128;

    float acc[8][8] = {};

    for (int d0 = 0; d0 < DIM; d0 += 16) {
#pragma unroll
        for (int u = 0; u < 2; ++u) {
            int f4  = u * 256 + t;           // 0..511
            int row = f4 >> 2;               // 0..127
            int cp  = (f4 & 3) * 4;          // 0,4,8,12
            float4 v = *reinterpret_cast<const float4*>(x  + (size_t)(n0 + row) * DIM + d0 + cp);
            Xs[cp + 0][row] = v.x; Xs[cp + 1][row] = v.y;
            Xs[cp + 2][row] = v.z; Xs[cp + 3][row] = v.w;
            float4 w = *reinterpret_cast<const float4*>(cb + (size_t)(k0 + row) * DIM + d0 + cp);
            Cs[cp + 0][row] = w.x; Cs[cp + 1][row] = w.y;
            Cs[cp + 2][row] = w.z; Cs[cp + 3][row] = w.w;
        }
        __syncthreads();
#pragma unroll
        for (int kk = 0; kk < 16; ++kk) {
            float a[8], b[8];
            *reinterpret_cast<float4*>(&a[0]) = *reinterpret_cast<const float4*>(&Xs[kk][ty * 4]);
            *reinterpret_cast<float4*>(&a[4]) = *reinterpret_cast<const float4*>(&Xs[kk][64 + ty * 4]);
            *reinterpret_cast<float4*>(&b[0]) = *reinterpret_cast<const float4*>(&Cs[kk][tx * 4]);
            *reinterpret_cast<float4*>(&b[4]) = *reinterpret_cast<const float4*>(&Cs[kk][64 + tx * 4]);
#pragma unroll
            for (int i = 0; i < 8; ++i)
#pragma unroll
                for (int jj = 0; jj < 8; ++jj)
                    acc[i][jj] = fmaf(a[i], b[jj], acc[i][jj]);
        }
        __syncthreads();
    }

    // epilogue: sq = (xn + cn) - 2*s ; dist = sqrt(max(sq,0))
    float cnv[8];
#pragma unroll
    for (int jh = 0; jh < 2; ++jh)
#pragma unroll
        for (int jj = 0; jj < 4; ++jj)
            cnv[jh * 4 + jj] = cnorm[k0 + jh * 64 + tx * 4 + jj];

#pragma unroll
    for (int ih = 0; ih < 2; ++ih) {
#pragma unroll
        for (int i = 0; i < 4; ++i) {
            int r = n0 + ih * 64 + ty * 4 + i;
            float xnv = xnorm[r];
            float* orow = dist_out + (size_t)r * KCB + k0;
#pragma unroll
            for (int jh = 0; jh < 2; ++jh) {
                float4 o;
                o.x = sqrtf(fmaxf((xnv + cnv[jh * 4 + 0]) - 2.0f * acc[ih * 4 + i][jh * 4 + 0], 0.0f));
                o.y = sqrtf(fmaxf((xnv + cnv[jh * 4 + 1]) - 2.0f * acc[ih * 4 + i][jh * 4 + 1], 0.0f));
                o.z = sqrtf(fmaxf((xnv + cnv[jh * 4 + 2]) - 2.0f * acc[ih * 4 + i][jh * 4 + 2], 0.0f));
                o.w = sqrtf(fmaxf((xnv + cnv[jh * 4 + 3]) - 2.0f * acc[ih * 4 + i][jh * 4 + 3], 0.0f));
                *reinterpret_cast<float4*>(orow + jh * 64 + tx * 4) = o;
            }
        }
    }
}

// ---------------------------------------------------------------------------
// K2: per-token row pass. Reads dist (in enc region) + noise, computes
// e = exp(noise - dist), Z = sum e, writes enc = e/Z in place, and the argmin
// index. Argmin is re-derived from np-faithful distances (serial ascending
// fma dot + numpy-exact norms + matching rounding order) for all codes within
// MARGIN of the row min, with first-index tie-break == np.argmin semantics.
// ---------------------------------------------------------------------------
__global__ __launch_bounds__(256) void rowpass_kernel(
    float* __restrict__ enc,            // in: dist, out: encodings
    const float* __restrict__ noise,
    const float* __restrict__ x, const float* __restrict__ cb,
    const float* __restrict__ xnorm, const float* __restrict__ cnorm,
    float* __restrict__ idx_out) {
#pragma clang fp contract(off)
    const int n = blockIdx.x;
    const int t = threadIdx.x;
    float* row = enc + (size_t)n * KCB;
    const float* nrow = noise + (size_t)n * KCB;

    float dist[16], ee[16];
    float dmin = 3.402823466e38f;
    int   kmin = 0x7fffffff;
    float lsum = 0.0f;

#pragma unroll
    for (int u = 0; u < 4; ++u) {
        int f4 = u * 256 + t;
        float4 dv = *reinterpret_cast<const float4*>(row  + f4 * 4);
        float4 nv = *reinterpret_cast<const float4*>(nrow + f4 * 4);
        float d_[4] = {dv.x, dv.y, dv.z, dv.w};
        float n_[4] = {nv.x, nv.y, nv.z, nv.w};
#pragma unroll
        for (int j = 0; j < 4; ++j) {
            int k = f4 * 4 + j;
            float d = d_[j];
            float e = expf(n_[j] - d);   // TAU == 1
            dist[u * 4 + j] = d;
            ee[u * 4 + j] = e;
            lsum += e;
            if (d < dmin || (d == dmin && k < kmin)) { dmin = d; kmin = k; }
        }
    }

    __shared__ float sv[256];
    __shared__ int   si[256];
    __shared__ float ss[256];
    sv[t] = dmin; si[t] = kmin; ss[t] = lsum;
    __syncthreads();
    for (int s = 128; s > 0; s >>= 1) {
        if (t < s) {
            ss[t] += ss[t + s];
            float v2 = sv[t + s]; int i2 = si[t + s];
            if (v2 < sv[t] || (v2 == sv[t] && i2 < si[t])) { sv[t] = v2; si[t] = i2; }
        }
        __syncthreads();
    }
    const float rmin = sv[0];
    const float Z    = ss[0];

    // candidate recheck: np-faithful distance for everything near the min
    const float margin = rmin + 1.0e-3f;
    float cv = 3.402823466e38f;
    int   ck = 0x7fffffff;
    const float xn = xnorm[n];
    const float* xr = x + (size_t)n * DIM;
#pragma unroll
    for (int u = 0; u < 4; ++u) {
#pragma unroll
        for (int j = 0; j < 4; ++j) {
            if (dist[u * 4 + j] <= margin) {
                int k = (u * 256 + t) * 4 + j;
                const float* cr = cb + (size_t)k * DIM;
                float acc = 0.0f;
                for (int d2 = 0; d2 < DIM; ++d2)
                    acc = __builtin_fmaf(xr[d2], cr[d2], acc);  // BLAS-style serial fma
                float sq  = (xn + cnorm[k]) - 2.0f * acc;       // np rounding order
                float dnp = sqrtf(fmaxf(sq, 0.0f));
                if (dnp < cv || (dnp == cv && k < ck)) { cv = dnp; ck = k; }
            }
        }
    }
    __syncthreads();
    sv[t] = cv; si[t] = ck;
    __syncthreads();
    for (int s = 128; s > 0; s >>= 1) {
        if (t < s) {
            float v2 = sv[t + s]; int i2 = si[t + s];
            if (v2 < sv[t] || (v2 == sv[t] && i2 < si[t])) { sv[t] = v2; si[t] = i2; }
        }
        __syncthreads();
    }
    if (t == 0) idx_out[n] = (float)si[0];

    const float invZ = 1.0f / Z;
#pragma unroll
    for (int u = 0; u < 4; ++u) {
        int f4 = u * 256 + t;
        float4 o;
        o.x = ee[u * 4 + 0] * invZ;
        o.y = ee[u * 4 + 1] * invZ;
        o.z = ee[u * 4 + 2] * invZ;
        o.w = ee[u * 4 + 3] * invZ;
        *reinterpret_cast<float4*>(row + f4 * 4) = o;
    }
}

// ---------------------------------------------------------------------------
// K3: quantized = E (N x K) * C (K x D), fp32 GEMM-NN.
// 64x256 block tile (full D per block so E is read exactly once), 256
// threads, 8x8 micro-tile.
// ---------------------------------------------------------------------------
__global__ __launch_bounds__(256) void gemm2_kernel(
    const float* __restrict__ enc, const float* __restrict__ cb,
    float* __restrict__ q) {
    __shared__ float Es[16][68];
    __shared__ float Cs[16][260];

    const int t  = threadIdx.x;
    const int tn = t & 31, tm = t >> 5;
    const int n0 = blockIdx.x * 64;

    float acc[8][8] = {};

    for (int kq0 = 0; kq0 < KCB; kq0 += 16) {
        {   // E tile: 64 rows x 16 cols, transposed into LDS
            int r  = t >> 2;
            int cp = (t & 3) * 4;
            float4 v = *reinterpret_cast<const float4*>(enc + (size_t)(n0 + r) * KCB + kq0 + cp);
            Es[cp + 0][r] = v.x; Es[cp + 1][r] = v.y;
            Es[cp + 2][r] = v.z; Es[cp + 3][r] = v.w;
        }
#pragma unroll
        for (int u = 0; u < 4; ++u) {   // C tile: 16 rows x 256 cols, direct
            int f4 = u * 256 + t;
            int r  = f4 >> 6;
            int c  = (f4 & 63) * 4;
            *reinterpret_cast<float4*>(&Cs[r][c]) =
                *reinterpret_cast<const float4*>(cb + (size_t)(kq0 + r) * DIM + c);
        }
        __syncthreads();
#pragma unroll
        for (int kk = 0; kk < 16; ++kk) {
            float a[8], b[8];
            *reinterpret_cast<float4*>(&a[0]) = *reinterpret_cast<const float4*>(&Es[kk][tm * 4]);
            *reinterpret_cast<float4*>(&a[4]) = *reinterpret_cast<const float4*>(&Es[kk][32 + tm * 4]);
            *reinterpret_cast<float4*>(&b[0]) = *reinterpret_cast<const float4*>(&Cs[kk][tn * 4]);
            *reinterpret_cast<float4*>(&b[4]) = *reinterpret_cast<const float4*>(&Cs[kk][128 + tn * 4]);
#pragma unroll
            for (int i = 0; i < 8; ++i)
#pragma unroll
                for (int jj = 0; jj < 8; ++jj)
                    acc[i][jj] = fmaf(a[i], b[jj], acc[i][jj]);
        }
        __syncthreads();
    }

#pragma unroll
    for (int ih = 0; ih < 2; ++ih) {
#pragma unroll
        for (int i = 0; i < 4; ++i) {
            int r = n0 + ih * 32 + tm * 4 + i;
#pragma unroll
            for (int jh = 0; jh < 2; ++jh) {
                float4 o;
                o.x = acc[ih * 4 + i][jh * 4 + 0];
                o.y = acc[ih * 4 + i][jh * 4 + 1];
                o.z = acc[ih * 4 + i][jh * 4 + 2];
                o.w = acc[ih * 4 + i][jh * 4 + 3];
                *reinterpret_cast<float4*>(q + (size_t)r * DIM + jh * 128 + tn * 4) = o;
            }
        }
    }
}

// ---------------------------------------------------------------------------
extern "C" void kernel_launch(void* const* d_in, const int* in_sizes, int n_in,
                              void* d_out, int out_size, void* d_ws, size_t ws_size,
                              hipStream_t stream) {
    const float* x     = (const float*)d_in[0];
    const float* cb    = (const float*)d_in[1];
    const float* noise = (const float*)d_in[2];

    float* out = (float*)d_out;
    float* q   = out;                                   // N*D
    float* enc = out + (size_t)NTOK * DIM;              // N*K
    float* idx = enc + (size_t)NTOK * KCB;              // N

    // scratch aliases inside d_out (no d_ws dependence):
    //   xnorm lives in the idx region (overwritten by rowpass at the end)
    //   cnorm lives in the quantized region (overwritten by gemm2 at the end)
    float* xnorm = idx;
    float* cnorm = q;

    norms_kernel<<<(NTOK + KCB) * 16 / 256, 256, 0, stream>>>(x, cb, xnorm, cnorm);

    dim3 g1(KCB / 128, NTOK / 128);
    gemm1_kernel<<<g1, 256, 0, stream>>>(x, cb, xnorm, cnorm, enc);

    rowpass_kernel<<<NTOK, 256, 0, stream>>>(enc, noise, x, cb, xnorm, cnorm, idx);

    gemm2_kernel<<<NTOK / 64, 256, 0, stream>>>(enc, cb, q);
}